// Round 6
// baseline (160.094 us; speedup 1.0000x reference)
//
#include <hip/hip_runtime.h>
#include <math.h>

#define DIM     1024
#define NSTAGES 10
#define HALFD   512                   // angles per stage = DIM/2
#define TABN    (NSTAGES * HALFD)     // 5120 floats per table

// ---------------------------------------------------------------------------
// Prep: cos/sin tables into workspace. ws layout: cos[10][512] | sin[10][512]
// ---------------------------------------------------------------------------
__global__ void bf_prep(const float* __restrict__ ang, float* __restrict__ ws) {
    int i = blockIdx.x * blockDim.x + threadIdx.x;
    if (i < TABN) {
        float s, c;
        sincosf(ang[i], &s, &c);
        ws[i]        = c;
        ws[TABN + i] = s;
    }
}

// ---------------------------------------------------------------------------
// Main butterfly. Lane owns elements e = 256*c + 4*lane + d of each row.
//   stage 0,1  : intra-float4
//   stage 2..7 : cross-lane, shfl_xor mask m = 1<<(s-2)  (1..32)
//   stage 8,9  : intra-lane across c-groups
// Angle index for left element i at stage s: p = ((i>>(s+1))<<s) | (i&(half-1))
//
// Structure (lessons R1..R5):
//  - cos/sin table in LDS (DS-pipe reads, low latency)   [R1 vs R5: +11.3us]
//  - 4 rows/wave as 2 fenced batches of 2: fence blocks table-load CSE
//    across batches (R3 256-VGPR blowup / R4 spill failure mode)
//  - staging loads issue before payload loads; payload in flight across
//    the barrier
//  - launch_bounds(256,4): VGPR<=128 -> 4 waves/SIMD
//  - grid=1024 blocks, 40KB LDS -> 4 blocks/CU -> whole grid resident
// ---------------------------------------------------------------------------
__global__ __launch_bounds__(256, 4) void bf_main(
    const float* __restrict__ x,
    const float* __restrict__ tab,
    float* __restrict__ out)
{
    __shared__ __align__(16) float cosT[TABN];
    __shared__ __align__(16) float sinT[TABN];
    const int tid  = threadIdx.x;
    const int lane = tid & 63;
    const int gwid = blockIdx.x * 4 + (tid >> 6);   // global wave id, 4 rows each

    // ---- stage table: 10 float4 global loads/thread (issued FIRST) -------
    {
        const float4* s4 = (const float4*)tab;
        float4* c4 = (float4*)cosT;
        float4* n4 = (float4*)sinT;
        #pragma unroll
        for (int i = 0; i < TABN / 4 / 256; ++i) {   // 5 iterations
            const int idx = i * 256 + tid;
            c4[idx] = s4[idx];
            n4[idx] = s4[TABN / 4 + idx];
        }
    }

    // ---- payload: all 4 rows loaded up front (in flight across barrier) --
    const float4* xp = (const float4*)x   + (size_t)gwid * 4 * (DIM / 4) + lane;
    float4*       op = (float4*)      out + (size_t)gwid * 4 * (DIM / 4) + lane;
    float4 v[4][4];
    #pragma unroll
    for (int r = 0; r < 4; ++r)
        #pragma unroll
        for (int c = 0; c < 4; ++c)
            v[r][c] = xp[r * 256 + c * 64];

    __syncthreads();

    #pragma unroll 1
    for (int b = 0; b < 2; ++b) {
        asm volatile("" ::: "memory");   // no table-load hoist/CSE across batches
        const int r0 = 2 * b;

        // ---- stages 0,1: intra-float4. p = 128c + 2*lane + {0,1} ---------
        #pragma unroll
        for (int s01 = 0; s01 < 2; ++s01) {
            const float* cT = cosT + s01 * HALFD;
            const float* sT = sinT + s01 * HALFD;
            #pragma unroll
            for (int c = 0; c < 4; ++c) {
                const int p = 128 * c + 2 * lane;
                float2 cc = *(const float2*)&cT[p];
                float2 ss = *(const float2*)&sT[p];
                #pragma unroll
                for (int rr = 0; rr < 2; ++rr) {
                    float4 u = v[r0 + rr][c];
                    if (s01 == 0) {
                        v[r0 + rr][c].x = cc.x * u.x + ss.x * u.y;
                        v[r0 + rr][c].y = cc.x * u.y - ss.x * u.x;
                        v[r0 + rr][c].z = cc.y * u.z + ss.y * u.w;
                        v[r0 + rr][c].w = cc.y * u.w - ss.y * u.z;
                    } else {
                        v[r0 + rr][c].x = cc.x * u.x + ss.x * u.z;
                        v[r0 + rr][c].z = cc.x * u.z - ss.x * u.x;
                        v[r0 + rr][c].y = cc.y * u.y + ss.y * u.w;
                        v[r0 + rr][c].w = cc.y * u.w - ss.y * u.y;
                    }
                }
            }
        }

        // ---- stages 2..7: cross-lane via shfl_xor ------------------------
        #pragma unroll
        for (int s = 2; s <= 7; ++s) {
            const int m = 1 << (s - 2);
            const float* cT = cosT + s * HALFD;
            const float* sT = sinT + s * HALFD;
            const int l0 = lane & ~m;               // left lane of the pair
            const float sgn = (lane & m) ? -1.0f : 1.0f;
            #pragma unroll
            for (int c = 0; c < 4; ++c) {
                const int p0 = (((c << (7 - s)) + (l0 >> (s - 1))) << s)
                             + 4 * (l0 & (m - 1));
                float4 C = *(const float4*)&cT[p0];
                float4 S = *(const float4*)&sT[p0];
                S.x *= sgn; S.y *= sgn; S.z *= sgn; S.w *= sgn;
                #pragma unroll
                for (int rr = 0; rr < 2; ++rr) {
                    float4 u = v[r0 + rr][c];
                    float tx = __shfl_xor(u.x, m, 64);
                    float ty = __shfl_xor(u.y, m, 64);
                    float tz = __shfl_xor(u.z, m, 64);
                    float tw = __shfl_xor(u.w, m, 64);
                    v[r0 + rr][c].x = C.x * u.x + S.x * tx;
                    v[r0 + rr][c].y = C.y * u.y + S.y * ty;
                    v[r0 + rr][c].z = C.z * u.z + S.z * tz;
                    v[r0 + rr][c].w = C.w * u.w + S.w * tw;
                }
            }
        }

        // ---- stage 8: pairs (c0,c1),(c2,c3); p = 256*g + 4*lane + d ------
        {
            const float* cT = cosT + 8 * HALFD;
            const float* sT = sinT + 8 * HALFD;
            #pragma unroll
            for (int g = 0; g < 2; ++g) {
                const int p0 = 256 * g + 4 * lane;
                float4 C = *(const float4*)&cT[p0];
                float4 S = *(const float4*)&sT[p0];
                #pragma unroll
                for (int rr = 0; rr < 2; ++rr) {
                    float4 L = v[r0 + rr][2 * g], Rr = v[r0 + rr][2 * g + 1];
                    v[r0 + rr][2 * g].x     = C.x * L.x + S.x * Rr.x;
                    v[r0 + rr][2 * g].y     = C.y * L.y + S.y * Rr.y;
                    v[r0 + rr][2 * g].z     = C.z * L.z + S.z * Rr.z;
                    v[r0 + rr][2 * g].w     = C.w * L.w + S.w * Rr.w;
                    v[r0 + rr][2 * g + 1].x = C.x * Rr.x - S.x * L.x;
                    v[r0 + rr][2 * g + 1].y = C.y * Rr.y - S.y * L.y;
                    v[r0 + rr][2 * g + 1].z = C.z * Rr.z - S.z * L.z;
                    v[r0 + rr][2 * g + 1].w = C.w * Rr.w - S.w * L.w;
                }
            }
        }

        // ---- stage 9: pairs (c0,c2),(c1,c3) ------------------------------
        {
            const float* cT = cosT + 9 * HALFD;
            const float* sT = sinT + 9 * HALFD;
            #pragma unroll
            for (int g = 0; g < 2; ++g) {
                const int p0 = 256 * g + 4 * lane;
                float4 C = *(const float4*)&cT[p0];
                float4 S = *(const float4*)&sT[p0];
                #pragma unroll
                for (int rr = 0; rr < 2; ++rr) {
                    float4 L = v[r0 + rr][g], Rr = v[r0 + rr][g + 2];
                    v[r0 + rr][g].x     = C.x * L.x + S.x * Rr.x;
                    v[r0 + rr][g].y     = C.y * L.y + S.y * Rr.y;
                    v[r0 + rr][g].z     = C.z * L.z + S.z * Rr.z;
                    v[r0 + rr][g].w     = C.w * L.w + S.w * Rr.w;
                    v[r0 + rr][g + 2].x = C.x * Rr.x - S.x * L.x;
                    v[r0 + rr][g + 2].y = C.y * Rr.y - S.y * L.y;
                    v[r0 + rr][g + 2].z = C.z * Rr.z - S.z * L.z;
                    v[r0 + rr][g + 2].w = C.w * Rr.w - S.w * L.w;
                }
            }
        }

        // ---- store this batch's 2 rows -----------------------------------
        #pragma unroll
        for (int rr = 0; rr < 2; ++rr)
            #pragma unroll
            for (int c = 0; c < 4; ++c)
                op[(r0 + rr) * 256 + c * 64] = v[r0 + rr][c];
    }
}

extern "C" void kernel_launch(void* const* d_in, const int* in_sizes, int n_in,
                              void* d_out, int out_size, void* d_ws, size_t ws_size,
                              hipStream_t stream) {
    const float* x   = (const float*)d_in[0];
    const float* ang = (const float*)d_in[1];
    float* out = (float*)d_out;

    const int nrows = out_size / DIM;          // 16384
    // 4 waves/block x 4 rows/wave = 16 rows/block -> 1024 blocks,
    // 4 blocks/CU at 40KB LDS -> whole grid resident in one round.
    const int nblocks = nrows / 16;

    float* tab = (float*)d_ws;                 // 40 KB
    bf_prep<<<(TABN + 255) / 256, 256, 0, stream>>>(ang, tab);
    bf_main<<<nblocks, 256, 0, stream>>>(x, tab, out);
}

// Round 7
// 141.791 us; speedup vs baseline: 1.1291x; 1.1291x over previous
//
#include <hip/hip_runtime.h>
#include <math.h>

#define DIM     1024
#define NSTAGES 10
#define HALFD   512                   // angles per stage = DIM/2
#define TABN    (NSTAGES * HALFD)     // 5120 floats per table

// ---------------------------------------------------------------------------
// Prep: cos/sin tables into workspace. ws layout: cos[10][512] | sin[10][512]
// ---------------------------------------------------------------------------
__global__ void bf_prep(const float* __restrict__ ang, float* __restrict__ ws) {
    int i = blockIdx.x * blockDim.x + threadIdx.x;
    if (i < TABN) {
        float s, c;
        sincosf(ang[i], &s, &c);
        ws[i]        = c;
        ws[TABN + i] = s;
    }
}

// ---------------------------------------------------------------------------
// Cross-lane xor exchange, cheapest pipe per mask:
//   m=1,2  : DPP quad_perm            (VALU, no DS slot)
//   m=4,8,16: ds_swizzle BitMode xor  (1 DS op, no addr VGPR)
//   m=32   : __shfl_xor               (DS)
// ---------------------------------------------------------------------------
__device__ __forceinline__ float xor1(float f) {   // quad_perm [1,0,3,2] = 0xB1
    return __builtin_bit_cast(float,
        __builtin_amdgcn_update_dpp(0, __builtin_bit_cast(int, f), 0xB1, 0xF, 0xF, true));
}
__device__ __forceinline__ float xor2(float f) {   // quad_perm [2,3,0,1] = 0x4E
    return __builtin_bit_cast(float,
        __builtin_amdgcn_update_dpp(0, __builtin_bit_cast(int, f), 0x4E, 0xF, 0xF, true));
}
__device__ __forceinline__ float xor4(float f) {   // (4<<10)|0x1F
    return __builtin_bit_cast(float,
        __builtin_amdgcn_ds_swizzle(__builtin_bit_cast(int, f), 0x101F));
}
__device__ __forceinline__ float xor8(float f) {   // (8<<10)|0x1F
    return __builtin_bit_cast(float,
        __builtin_amdgcn_ds_swizzle(__builtin_bit_cast(int, f), 0x201F));
}
__device__ __forceinline__ float xor16(float f) {  // (16<<10)|0x1F
    return __builtin_bit_cast(float,
        __builtin_amdgcn_ds_swizzle(__builtin_bit_cast(int, f), 0x401F));
}
__device__ __forceinline__ float xor32(float f) {
    return __shfl_xor(f, 32, 64);
}

// one cross-lane stage S (2..7), applied to all 4 rows; XORF picked per mask
#define XSTAGE(S, XORF)                                                    \
    {                                                                      \
        constexpr int m = 1 << ((S) - 2);                                  \
        const float* cT = cosT + (S) * HALFD;                              \
        const float* sT = sinT + (S) * HALFD;                              \
        const int l0 = lane & ~m;                                          \
        const float sgn = (lane & m) ? -1.0f : 1.0f;                       \
        _Pragma("unroll")                                                  \
        for (int c = 0; c < 4; ++c) {                                      \
            const int p0 = (((c << (7 - (S))) + (l0 >> ((S) - 1))) << (S)) \
                         + 4 * (l0 & (m - 1));                             \
            float4 C = *(const float4*)&cT[p0];                            \
            float4 Sv = *(const float4*)&sT[p0];                           \
            Sv.x *= sgn; Sv.y *= sgn; Sv.z *= sgn; Sv.w *= sgn;            \
            _Pragma("unroll")                                              \
            for (int r = 0; r < 4; ++r) {                                  \
                float4 u = v[r][c];                                        \
                float tx = XORF(u.x), ty = XORF(u.y);                      \
                float tz = XORF(u.z), tw = XORF(u.w);                      \
                v[r][c].x = C.x * u.x + Sv.x * tx;                         \
                v[r][c].y = C.y * u.y + Sv.y * ty;                         \
                v[r][c].z = C.z * u.z + Sv.z * tz;                         \
                v[r][c].w = C.w * u.w + Sv.w * tw;                         \
            }                                                              \
        }                                                                  \
    }

// ---------------------------------------------------------------------------
// Main butterfly. Lane owns elements e = 256*c + 4*lane + d of each row.
//   stage 0,1  : intra-float4
//   stage 2..7 : cross-lane xor exchanges (see above)
//   stage 8,9  : intra-lane across c-groups
// One 4-row batch per wave, fully static indexing (no runtime-indexed v ->
// no scratch [R6], no batch loop -> no cross-batch CSE [R3]).
// Staging loop unroll(1): 2 loads in flight, not 10 [R4's pre-barrier bomb].
// Grid 1024 blocks x 40KB LDS = exactly 4 blocks/CU, whole grid resident.
// ---------------------------------------------------------------------------
__global__ __launch_bounds__(256, 4) void bf_main(
    const float* __restrict__ x,
    const float* __restrict__ tab,
    float* __restrict__ out)
{
    __shared__ __align__(16) float cosT[TABN];
    __shared__ __align__(16) float sinT[TABN];
    const int tid  = threadIdx.x;
    const int lane = tid & 63;
    const int gwid = blockIdx.x * 4 + (tid >> 6);   // global wave id, 4 rows each

    // ---- stage table into LDS: unroll(1), low in-flight register cost ----
    {
        const float4* s4 = (const float4*)tab;
        float4* c4 = (float4*)cosT;
        float4* n4 = (float4*)sinT;
        #pragma unroll 1
        for (int i = 0; i < TABN / 4 / 256; ++i) {   // 5 iterations
            const int idx = i * 256 + tid;
            c4[idx] = s4[idx];
            n4[idx] = s4[TABN / 4 + idx];
        }
    }

    // ---- payload: 4 rows, in flight across the barrier -------------------
    const float4* xp = (const float4*)x   + (size_t)gwid * 4 * (DIM / 4) + lane;
    float4*       op = (float4*)      out + (size_t)gwid * 4 * (DIM / 4) + lane;
    float4 v[4][4];
    #pragma unroll
    for (int r = 0; r < 4; ++r)
        #pragma unroll
        for (int c = 0; c < 4; ++c)
            v[r][c] = xp[r * 256 + c * 64];

    __syncthreads();

    // ---- stages 0,1: intra-float4. p = 128c + 2*lane + {0,1} -------------
    #pragma unroll
    for (int s01 = 0; s01 < 2; ++s01) {
        const float* cT = cosT + s01 * HALFD;
        const float* sT = sinT + s01 * HALFD;
        #pragma unroll
        for (int c = 0; c < 4; ++c) {
            const int p = 128 * c + 2 * lane;
            float2 cc = *(const float2*)&cT[p];
            float2 ss = *(const float2*)&sT[p];
            #pragma unroll
            for (int r = 0; r < 4; ++r) {
                float4 u = v[r][c];
                if (s01 == 0) {
                    v[r][c].x = cc.x * u.x + ss.x * u.y;
                    v[r][c].y = cc.x * u.y - ss.x * u.x;
                    v[r][c].z = cc.y * u.z + ss.y * u.w;
                    v[r][c].w = cc.y * u.w - ss.y * u.z;
                } else {
                    v[r][c].x = cc.x * u.x + ss.x * u.z;
                    v[r][c].z = cc.x * u.z - ss.x * u.x;
                    v[r][c].y = cc.y * u.y + ss.y * u.w;
                    v[r][c].w = cc.y * u.w - ss.y * u.y;
                }
            }
        }
    }

    // ---- stages 2..7: cross-lane exchanges -------------------------------
    XSTAGE(2, xor1)
    XSTAGE(3, xor2)
    XSTAGE(4, xor4)
    XSTAGE(5, xor8)
    XSTAGE(6, xor16)
    XSTAGE(7, xor32)

    // ---- stage 8: pairs (c0,c1),(c2,c3); p = 256*g + 4*lane + d ----------
    {
        const float* cT = cosT + 8 * HALFD;
        const float* sT = sinT + 8 * HALFD;
        #pragma unroll
        for (int g = 0; g < 2; ++g) {
            const int p0 = 256 * g + 4 * lane;
            float4 C = *(const float4*)&cT[p0];
            float4 S = *(const float4*)&sT[p0];
            #pragma unroll
            for (int r = 0; r < 4; ++r) {
                float4 L = v[r][2 * g], Rr = v[r][2 * g + 1];
                v[r][2 * g].x     = C.x * L.x + S.x * Rr.x;
                v[r][2 * g].y     = C.y * L.y + S.y * Rr.y;
                v[r][2 * g].z     = C.z * L.z + S.z * Rr.z;
                v[r][2 * g].w     = C.w * L.w + S.w * Rr.w;
                v[r][2 * g + 1].x = C.x * Rr.x - S.x * L.x;
                v[r][2 * g + 1].y = C.y * Rr.y - S.y * L.y;
                v[r][2 * g + 1].z = C.z * Rr.z - S.z * L.z;
                v[r][2 * g + 1].w = C.w * Rr.w - S.w * L.w;
            }
        }
    }

    // ---- stage 9: pairs (c0,c2),(c1,c3) ----------------------------------
    {
        const float* cT = cosT + 9 * HALFD;
        const float* sT = sinT + 9 * HALFD;
        #pragma unroll
        for (int g = 0; g < 2; ++g) {
            const int p0 = 256 * g + 4 * lane;
            float4 C = *(const float4*)&cT[p0];
            float4 S = *(const float4*)&sT[p0];
            #pragma unroll
            for (int r = 0; r < 4; ++r) {
                float4 L = v[r][g], Rr = v[r][g + 2];
                v[r][g].x     = C.x * L.x + S.x * Rr.x;
                v[r][g].y     = C.y * L.y + S.y * Rr.y;
                v[r][g].z     = C.z * L.z + S.z * Rr.z;
                v[r][g].w     = C.w * L.w + S.w * Rr.w;
                v[r][g + 2].x = C.x * Rr.x - S.x * L.x;
                v[r][g + 2].y = C.y * Rr.y - S.y * L.y;
                v[r][g + 2].z = C.z * Rr.z - S.z * L.z;
                v[r][g + 2].w = C.w * Rr.w - S.w * L.w;
            }
        }
    }

    // ---- store 4 rows -----------------------------------------------------
    #pragma unroll
    for (int r = 0; r < 4; ++r)
        #pragma unroll
        for (int c = 0; c < 4; ++c)
            op[r * 256 + c * 64] = v[r][c];
}

extern "C" void kernel_launch(void* const* d_in, const int* in_sizes, int n_in,
                              void* d_out, int out_size, void* d_ws, size_t ws_size,
                              hipStream_t stream) {
    const float* x   = (const float*)d_in[0];
    const float* ang = (const float*)d_in[1];
    float* out = (float*)d_out;

    const int nrows = out_size / DIM;          // 16384
    // 4 waves/block x 4 rows/wave = 16 rows/block -> 1024 blocks,
    // 4 blocks/CU at 40KB LDS -> whole grid resident in one round.
    const int nblocks = nrows / 16;

    float* tab = (float*)d_ws;                 // 40 KB
    bf_prep<<<(TABN + 255) / 256, 256, 0, stream>>>(ang, tab);
    bf_main<<<nblocks, 256, 0, stream>>>(x, tab, out);
}

// Round 8
// 35.142 us; speedup vs baseline: 4.5556x; 4.0348x over previous
//
#include <hip/hip_runtime.h>
#include <math.h>

#define DIM     1024
#define NSTAGES 10
#define HALFD   512                   // angles per stage = DIM/2
#define TABN    (NSTAGES * HALFD)     // 5120 floats per table

// ---------------------------------------------------------------------------
// Prep: cos/sin tables into workspace. ws layout: cos[10][512] | sin[10][512]
// ---------------------------------------------------------------------------
__global__ void bf_prep(const float* __restrict__ ang, float* __restrict__ ws) {
    int i = blockIdx.x * blockDim.x + threadIdx.x;
    if (i < TABN) {
        float s, c;
        sincosf(ang[i], &s, &c);
        ws[i]        = c;
        ws[TABN + i] = s;
    }
}

// ---------------------------------------------------------------------------
// Cross-lane xor exchange, cheapest pipe per mask (verified correct in R7):
//   m=1,2  : DPP quad_perm            (VALU, no DS slot)
//   m=4,8,16: ds_swizzle BitMode xor  (1 DS op, no addr VGPR)
//   m=32   : __shfl_xor               (DS)
// ---------------------------------------------------------------------------
__device__ __forceinline__ float xor1(float f) {   // quad_perm [1,0,3,2]
    return __builtin_bit_cast(float,
        __builtin_amdgcn_update_dpp(0, __builtin_bit_cast(int, f), 0xB1, 0xF, 0xF, true));
}
__device__ __forceinline__ float xor2(float f) {   // quad_perm [2,3,0,1]
    return __builtin_bit_cast(float,
        __builtin_amdgcn_update_dpp(0, __builtin_bit_cast(int, f), 0x4E, 0xF, 0xF, true));
}
__device__ __forceinline__ float xor4(float f) {
    return __builtin_bit_cast(float,
        __builtin_amdgcn_ds_swizzle(__builtin_bit_cast(int, f), 0x101F));
}
__device__ __forceinline__ float xor8(float f) {
    return __builtin_bit_cast(float,
        __builtin_amdgcn_ds_swizzle(__builtin_bit_cast(int, f), 0x201F));
}
__device__ __forceinline__ float xor16(float f) {
    return __builtin_bit_cast(float,
        __builtin_amdgcn_ds_swizzle(__builtin_bit_cast(int, f), 0x401F));
}
__device__ __forceinline__ float xor32(float f) {
    return __shfl_xor(f, 32, 64);
}

// one cross-lane stage S (2..7) applied to a 2-row batch; XORF per mask
#define XSTAGE(S, XORF)                                                    \
    {                                                                      \
        constexpr int m = 1 << ((S) - 2);                                  \
        const float* cT = cosT + (S) * HALFD;                              \
        const float* sT = sinT + (S) * HALFD;                              \
        const int l0 = lane & ~m;                                          \
        const float sgn = (lane & m) ? -1.0f : 1.0f;                       \
        _Pragma("unroll")                                                  \
        for (int c = 0; c < 4; ++c) {                                      \
            const int p0 = (((c << (7 - (S))) + (l0 >> ((S) - 1))) << (S)) \
                         + 4 * (l0 & (m - 1));                             \
            float4 C = *(const float4*)&cT[p0];                            \
            float4 Sv = *(const float4*)&sT[p0];                           \
            Sv.x *= sgn; Sv.y *= sgn; Sv.z *= sgn; Sv.w *= sgn;            \
            _Pragma("unroll")                                              \
            for (int r = 0; r < 2; ++r) {                                  \
                float4 u = v[r][c];                                        \
                float tx = XORF(u.x), ty = XORF(u.y);                      \
                float tz = XORF(u.z), tw = XORF(u.w);                      \
                v[r][c].x = C.x * u.x + Sv.x * tx;                         \
                v[r][c].y = C.y * u.y + Sv.y * ty;                         \
                v[r][c].z = C.z * u.z + Sv.z * tz;                         \
                v[r][c].w = C.w * u.w + Sv.w * tw;                         \
            }                                                              \
        }                                                                  \
    }

// ---------------------------------------------------------------------------
// Process one 2-row batch through all 10 stages (register working set:
// 32 data VGPRs + ~16 table/temp -> the proven no-spill size from R1/R5).
// ---------------------------------------------------------------------------
__device__ __forceinline__ void processBatch(float4 (&v)[2][4],
                                             const float* __restrict__ cosT,
                                             const float* __restrict__ sinT,
                                             int lane)
{
    // ---- stages 0,1: intra-float4. p = 128c + 2*lane + {0,1} -------------
    #pragma unroll
    for (int s01 = 0; s01 < 2; ++s01) {
        const float* cT = cosT + s01 * HALFD;
        const float* sT = sinT + s01 * HALFD;
        #pragma unroll
        for (int c = 0; c < 4; ++c) {
            const int p = 128 * c + 2 * lane;
            float2 cc = *(const float2*)&cT[p];
            float2 ss = *(const float2*)&sT[p];
            #pragma unroll
            for (int r = 0; r < 2; ++r) {
                float4 u = v[r][c];
                if (s01 == 0) {
                    v[r][c].x = cc.x * u.x + ss.x * u.y;
                    v[r][c].y = cc.x * u.y - ss.x * u.x;
                    v[r][c].z = cc.y * u.z + ss.y * u.w;
                    v[r][c].w = cc.y * u.w - ss.y * u.z;
                } else {
                    v[r][c].x = cc.x * u.x + ss.x * u.z;
                    v[r][c].z = cc.x * u.z - ss.x * u.x;
                    v[r][c].y = cc.y * u.y + ss.y * u.w;
                    v[r][c].w = cc.y * u.w - ss.y * u.y;
                }
            }
        }
    }

    // ---- stages 2..7: cross-lane exchanges -------------------------------
    XSTAGE(2, xor1)
    XSTAGE(3, xor2)
    XSTAGE(4, xor4)
    XSTAGE(5, xor8)
    XSTAGE(6, xor16)
    XSTAGE(7, xor32)

    // ---- stage 8: pairs (c0,c1),(c2,c3); p = 256*g + 4*lane + d ----------
    {
        const float* cT = cosT + 8 * HALFD;
        const float* sT = sinT + 8 * HALFD;
        #pragma unroll
        for (int g = 0; g < 2; ++g) {
            const int p0 = 256 * g + 4 * lane;
            float4 C = *(const float4*)&cT[p0];
            float4 S = *(const float4*)&sT[p0];
            #pragma unroll
            for (int r = 0; r < 2; ++r) {
                float4 L = v[r][2 * g], Rr = v[r][2 * g + 1];
                v[r][2 * g].x     = C.x * L.x + S.x * Rr.x;
                v[r][2 * g].y     = C.y * L.y + S.y * Rr.y;
                v[r][2 * g].z     = C.z * L.z + S.z * Rr.z;
                v[r][2 * g].w     = C.w * L.w + S.w * Rr.w;
                v[r][2 * g + 1].x = C.x * Rr.x - S.x * L.x;
                v[r][2 * g + 1].y = C.y * Rr.y - S.y * L.y;
                v[r][2 * g + 1].z = C.z * Rr.z - S.z * L.z;
                v[r][2 * g + 1].w = C.w * Rr.w - S.w * L.w;
            }
        }
    }

    // ---- stage 9: pairs (c0,c2),(c1,c3) ----------------------------------
    {
        const float* cT = cosT + 9 * HALFD;
        const float* sT = sinT + 9 * HALFD;
        #pragma unroll
        for (int g = 0; g < 2; ++g) {
            const int p0 = 256 * g + 4 * lane;
            float4 C = *(const float4*)&cT[p0];
            float4 S = *(const float4*)&sT[p0];
            #pragma unroll
            for (int r = 0; r < 2; ++r) {
                float4 L = v[r][g], Rr = v[r][g + 2];
                v[r][g].x     = C.x * L.x + S.x * Rr.x;
                v[r][g].y     = C.y * L.y + S.y * Rr.y;
                v[r][g].z     = C.z * L.z + S.z * Rr.z;
                v[r][g].w     = C.w * L.w + S.w * Rr.w;
                v[r][g + 2].x = C.x * Rr.x - S.x * L.x;
                v[r][g + 2].y = C.y * Rr.y - S.y * L.y;
                v[r][g + 2].z = C.z * Rr.z - S.z * L.z;
                v[r][g + 2].w = C.w * Rr.w - S.w * L.w;
            }
        }
    }
}

// ---------------------------------------------------------------------------
// Main: 1024 blocks x 4 waves, 4 rows/wave as TWO explicit 2-row batches
// with separate local arrays + a compiler fence between them (R5's proven
// no-spill codegen). LDS table (R1's proven win). Whole grid resident:
// 1024 blocks / 4 per CU (40KB LDS) = 256 CUs, one dispatch round.
// ---------------------------------------------------------------------------
__global__ __launch_bounds__(256) void bf_main(
    const float* __restrict__ x,
    const float* __restrict__ tab,
    float* __restrict__ out)
{
    __shared__ __align__(16) float cosT[TABN];
    __shared__ __align__(16) float sinT[TABN];
    const int tid  = threadIdx.x;
    const int lane = tid & 63;
    const int gwid = blockIdx.x * 4 + (tid >> 6);   // global wave id, 4 rows each

    // ---- stage table into LDS (10 float4 loads/thread, issued first) -----
    {
        const float4* s4 = (const float4*)tab;
        float4* c4 = (float4*)cosT;
        float4* n4 = (float4*)sinT;
        #pragma unroll
        for (int i = 0; i < TABN / 4 / 256; ++i) {   // 5 iterations
            const int idx = i * 256 + tid;
            c4[idx] = s4[idx];
            n4[idx] = s4[TABN / 4 + idx];
        }
    }

    const float4* xp = (const float4*)x   + (size_t)gwid * 4 * (DIM / 4) + lane;
    float4*       op = (float4*)      out + (size_t)gwid * 4 * (DIM / 4) + lane;

    // ---- batch 0: loads issued BEFORE the barrier (hidden under staging) --
    float4 v0[2][4];
    #pragma unroll
    for (int r = 0; r < 2; ++r)
        #pragma unroll
        for (int c = 0; c < 4; ++c)
            v0[r][c] = xp[r * 256 + c * 64];

    __syncthreads();

    {
        float4 (&v)[2][4] = v0;   // alias so XSTAGE sees `v`
        processBatch(v, cosT, sinT, lane);
    }
    #pragma unroll
    for (int r = 0; r < 2; ++r)
        #pragma unroll
        for (int c = 0; c < 4; ++c)
            op[r * 256 + c * 64] = v0[r][c];

    asm volatile("" ::: "memory");   // fence: no cross-batch hoist/CSE

    // ---- batch 1 ----------------------------------------------------------
    float4 v1[2][4];
    #pragma unroll
    for (int r = 0; r < 2; ++r)
        #pragma unroll
        for (int c = 0; c < 4; ++c)
            v1[r][c] = xp[(2 + r) * 256 + c * 64];

    {
        float4 (&v)[2][4] = v1;
        processBatch(v, cosT, sinT, lane);
    }
    #pragma unroll
    for (int r = 0; r < 2; ++r)
        #pragma unroll
        for (int c = 0; c < 4; ++c)
            op[(2 + r) * 256 + c * 64] = v1[r][c];
}

extern "C" void kernel_launch(void* const* d_in, const int* in_sizes, int n_in,
                              void* d_out, int out_size, void* d_ws, size_t ws_size,
                              hipStream_t stream) {
    const float* x   = (const float*)d_in[0];
    const float* ang = (const float*)d_in[1];
    float* out = (float*)d_out;

    const int nrows = out_size / DIM;          // 16384
    // 4 waves/block x 4 rows/wave = 16 rows/block -> 1024 blocks,
    // 4 blocks/CU at 40KB LDS -> whole grid resident in one round.
    const int nblocks = nrows / 16;

    float* tab = (float*)d_ws;                 // 40 KB
    bf_prep<<<(TABN + 255) / 256, 256, 0, stream>>>(ang, tab);
    bf_main<<<nblocks, 256, 0, stream>>>(x, tab, out);
}